// Round 11
// baseline (293.770 us; speedup 1.0000x reference)
//
#include <hip/hip_runtime.h>

#define NN 100000
#define NE 1600000
#define D 64
#define SCAN_BLK 1024
#define NSB ((NN + SCAN_BLK - 1) / SCAN_BLK)  // 98

// ---------------- ws layout (bytes), total 39,200,640 (same as proven) -----
// agg16  : [0, 12800000)            NN*D bf16
// rs     : [12800000, +400128)      NN+1 int
// cnt    : [13200128, +400000)      NN int (hist, then cursor)
// bsum   : [13600128, +512)         NSB int
// col_s  : [13600640, +6400000)     NE int   row-sorted cols
// val_s  : [20000640, +6400000)     NE f32   row-sorted vals
// feat16 : [26400640, +12800000)    NN*D bf16
static constexpr size_t OFF_AGG16 = 0;
static constexpr size_t OFF_RS    = 12800000;
static constexpr size_t OFF_CNT   = 13200128;
static constexpr size_t OFF_BS    = 13600128;
static constexpr size_t OFF_CS    = 13600640;
static constexpr size_t OFF_VS    = 20000640;
static constexpr size_t OFF_F16   = 26400640;

__device__ __forceinline__ unsigned short f32_to_bf16_rn(float x) {
    unsigned int u = __float_as_uint(x);
    u += 0x7FFFu + ((u >> 16) & 1u);  // round-to-nearest-even
    return (unsigned short)(u >> 16);
}
__device__ __forceinline__ float bf16_to_f32(unsigned int lo16) {
    return __uint_as_float(lo16 << 16);
}

// 0) feat f32 -> bf16 (8 elems/thread)
__global__ __launch_bounds__(256) void conv_k(const float* __restrict__ feat,
                                              unsigned short* __restrict__ feat16) {
    int i = blockIdx.x * blockDim.x + threadIdx.x;  // unit of 8 elems
    if (i >= NN * D / 8) return;
    const float4 f0 = *reinterpret_cast<const float4*>(&feat[i * 8]);
    const float4 f1 = *reinterpret_cast<const float4*>(&feat[i * 8 + 4]);
    uint4 o;
    o.x = f32_to_bf16_rn(f0.x) | ((unsigned int)f32_to_bf16_rn(f0.y) << 16);
    o.y = f32_to_bf16_rn(f0.z) | ((unsigned int)f32_to_bf16_rn(f0.w) << 16);
    o.z = f32_to_bf16_rn(f1.x) | ((unsigned int)f32_to_bf16_rn(f1.y) << 16);
    o.w = f32_to_bf16_rn(f1.z) | ((unsigned int)f32_to_bf16_rn(f1.w) << 16);
    *reinterpret_cast<uint4*>(&feat16[i * 8]) = o;
}

// 1) histogram of rows
__global__ __launch_bounds__(256) void hist_k(const int* __restrict__ rows,
                                              int* __restrict__ cnt) {
    int stride = gridDim.x * blockDim.x;
    for (int e = blockIdx.x * blockDim.x + threadIdx.x; e < NE; e += stride)
        atomicAdd(&cnt[rows[e]], 1);
}

// 2a) per-1024-block exclusive scan; block sums out
__global__ __launch_bounds__(256) void scan1_k(const int* __restrict__ cnt,
                                               int* __restrict__ rs,
                                               int* __restrict__ bsum) {
    __shared__ int tsum[256];
    const int b = blockIdx.x;
    const int base = b * SCAN_BLK + threadIdx.x * 4;
    int v[4];
    int s = 0;
#pragma unroll
    for (int i = 0; i < 4; ++i) {
        int idx = base + i;
        v[i] = (idx < NN) ? cnt[idx] : 0;
        s += v[i];
    }
    tsum[threadIdx.x] = s;
    __syncthreads();
    int x = s;
    for (int off = 1; off < 256; off <<= 1) {
        int y = (threadIdx.x >= off) ? tsum[threadIdx.x - off] : 0;
        __syncthreads();
        x += y;
        tsum[threadIdx.x] = x;
        __syncthreads();
    }
    int run = x - s;
#pragma unroll
    for (int i = 0; i < 4; ++i) {
        int idx = base + i;
        if (idx < NN) rs[idx] = run;
        run += v[i];
    }
    if (threadIdx.x == 255) bsum[b] = x;
}

// 2b) exclusive scan of NSB block sums
__global__ void scan2_k(int* __restrict__ bsum) {
    __shared__ int s[128];
    int i = threadIdx.x;
    int v = (i < NSB) ? bsum[i] : 0;
    s[i] = v;
    __syncthreads();
    int x = v;
    for (int off = 1; off < 128; off <<= 1) {
        int y = (i >= off) ? s[i - off] : 0;
        __syncthreads();
        x += y;
        s[i] = x;
        __syncthreads();
    }
    if (i < NSB) bsum[i] = x - v;  // exclusive
}

// 2c) add block offsets; cap entry
__global__ __launch_bounds__(256) void scan3_k(int* __restrict__ rs,
                                               const int* __restrict__ bsum) {
    int i = blockIdx.x * blockDim.x + threadIdx.x;
    if (i < NN) rs[i] += bsum[i >> 10];
    if (i == 0) rs[NN] = NE;
}

// 3) reorder edges into row-sorted arrays (two 4B stores — the int2-packed
//    variant regressed 2.5x: WRITE_SIZE 101 MB of unmerged line writebacks)
__global__ __launch_bounds__(256) void reorder_k(const int* __restrict__ rows,
                                                 const int* __restrict__ cols,
                                                 const float* __restrict__ vals,
                                                 const int* __restrict__ rs,
                                                 int* __restrict__ cur,
                                                 int* __restrict__ col_s,
                                                 float* __restrict__ val_s) {
    int stride = gridDim.x * blockDim.x;
    for (int e = blockIdx.x * blockDim.x + threadIdx.x; e < NE; e += stride) {
        int r = rows[e];
        int p = rs[r] + atomicAdd(&cur[r], 1);
        col_s[p] = cols[e];
        val_s[p] = vals[e];
    }
}

// 4) per-row gather-reduce, 8 edges in flight per wave, bf16 feat rows (128B
//    = 2 cache lines). lane = group g (lane>>3) x slot t (lane&7); group g
//    handles edge 8*jj+g; lane loads uint4 (8 bf16) of the neighbor row.
//    Cross-group shfl_xor(8,16,32) reduce; lanes 0-7 write the bf16 agg row.
__global__ __launch_bounds__(256) void gather_k(const int* __restrict__ rs,
                                                const int* __restrict__ col_s,
                                                const float* __restrict__ val_s,
                                                const unsigned short* __restrict__ feat16,
                                                unsigned short* __restrict__ agg16) {
    const int lane = threadIdx.x & 63;
    const int g = lane >> 3;
    const int t = lane & 7;
    const int r = blockIdx.x * 4 + (threadIdx.x >> 6);
    if (r >= NN) return;
    const int s = rs[r], e = rs[r + 1];

    float acc[8];
#pragma unroll
    for (int k = 0; k < 8; ++k) acc[k] = 0.f;

    for (int base = s; base < e; base += 64) {
        int n = e - base;
        if (n > 64) n = 64;
        int c = 0;
        float v = 0.f;
        if (lane < n) {
            c = col_s[base + lane];
            v = val_s[base + lane];
        }
        const int niter = (n + 7) >> 3;
        for (int jj = 0; jj < niter; ++jj) {
            int src = (jj << 3) + g;     // my group's edge slot
            int cj = __shfl(c, src);     // 0 if src >= n (row 0, harmless)
            float vj = __shfl(v, src);   // 0 if src >= n (no contribution)
            const uint4 f =
                *reinterpret_cast<const uint4*>(&feat16[(size_t)cj * D + (t << 3)]);
            acc[0] += vj * bf16_to_f32(f.x & 0xffffu);
            acc[1] += vj * bf16_to_f32(f.x >> 16);
            acc[2] += vj * bf16_to_f32(f.y & 0xffffu);
            acc[3] += vj * bf16_to_f32(f.y >> 16);
            acc[4] += vj * bf16_to_f32(f.z & 0xffffu);
            acc[5] += vj * bf16_to_f32(f.z >> 16);
            acc[6] += vj * bf16_to_f32(f.w & 0xffffu);
            acc[7] += vj * bf16_to_f32(f.w >> 16);
        }
    }
#pragma unroll
    for (int off = 8; off <= 32; off <<= 1) {
#pragma unroll
        for (int k = 0; k < 8; ++k) acc[k] += __shfl_xor(acc[k], off);
    }
    if (lane < 8) {
        uint4 o;
        o.x = f32_to_bf16_rn(acc[0]) | ((unsigned int)f32_to_bf16_rn(acc[1]) << 16);
        o.y = f32_to_bf16_rn(acc[2]) | ((unsigned int)f32_to_bf16_rn(acc[3]) << 16);
        o.z = f32_to_bf16_rn(acc[4]) | ((unsigned int)f32_to_bf16_rn(acc[5]) << 16);
        o.w = f32_to_bf16_rn(acc[6]) | ((unsigned int)f32_to_bf16_rn(acc[7]) << 16);
        *reinterpret_cast<uint4*>(&agg16[(size_t)r * D + (t << 3)]) = o;
    }
}

// 5) out = leaky(agg@W1+b1) + leaky((agg*feat)@W2+b2); agg in bf16
__global__ __launch_bounds__(256) void mlp_k(const unsigned short* __restrict__ agg16,
                                             const float* __restrict__ feat,
                                             const float* __restrict__ W1,
                                             const float* __restrict__ b1,
                                             const float* __restrict__ W2,
                                             const float* __restrict__ b2,
                                             float* __restrict__ out) {
    __shared__ float W1s[64 * 64];
    __shared__ float W2s[64 * 64];
    __shared__ float b1s[64], b2s[64];
    __shared__ float As[64][65];
    __shared__ float Ms[64][65];

    for (int i = threadIdx.x; i < 4096; i += 256) {
        W1s[i] = W1[i];
        W2s[i] = W2[i];
    }
    if (threadIdx.x < 64) {
        b1s[threadIdx.x] = b1[threadIdx.x];
        b2s[threadIdx.x] = b2[threadIdx.x];
    }

    const int wv = threadIdx.x >> 6;
    const int lane = threadIdx.x & 63;
    const int ntiles = (NN + 63) / 64;

    for (int t = blockIdx.x; t < ntiles; t += gridDim.x) {
        const int base = t * 64;
        __syncthreads();
        // stage: 64 rows x 8 segments of 8 elems; 512 units over 256 threads
        for (int i = threadIdx.x; i < 512; i += 256) {
            int row = i >> 3;
            int sg = i & 7;
            int n = base + row;
            uint4 a16 = make_uint4(0, 0, 0, 0);
            float4 f0 = make_float4(0.f, 0.f, 0.f, 0.f);
            float4 f1 = make_float4(0.f, 0.f, 0.f, 0.f);
            if (n < NN) {
                a16 = *reinterpret_cast<const uint4*>(&agg16[(size_t)n * D + sg * 8]);
                f0 = *reinterpret_cast<const float4*>(&feat[(size_t)n * D + sg * 8]);
                f1 = *reinterpret_cast<const float4*>(&feat[(size_t)n * D + sg * 8 + 4]);
            }
            float a[8];
            a[0] = bf16_to_f32(a16.x & 0xffffu);
            a[1] = bf16_to_f32(a16.x >> 16);
            a[2] = bf16_to_f32(a16.y & 0xffffu);
            a[3] = bf16_to_f32(a16.y >> 16);
            a[4] = bf16_to_f32(a16.z & 0xffffu);
            a[5] = bf16_to_f32(a16.z >> 16);
            a[6] = bf16_to_f32(a16.w & 0xffffu);
            a[7] = bf16_to_f32(a16.w >> 16);
            float f[8] = {f0.x, f0.y, f0.z, f0.w, f1.x, f1.y, f1.z, f1.w};
#pragma unroll
            for (int k = 0; k < 8; ++k) {
                As[row][sg * 8 + k] = a[k];
                Ms[row][sg * 8 + k] = a[k] * f[k];
            }
        }
        __syncthreads();

        const int dbase = wv * 16;
        float acc1[16], acc2[16];
#pragma unroll
        for (int j = 0; j < 16; ++j) {
            acc1[j] = b1s[dbase + j];
            acc2[j] = b2s[dbase + j];
        }
#pragma unroll 8
        for (int k = 0; k < 64; ++k) {
            float a = As[lane][k];
            float m = Ms[lane][k];
            const float4* w1p = reinterpret_cast<const float4*>(&W1s[k * 64 + dbase]);
            const float4* w2p = reinterpret_cast<const float4*>(&W2s[k * 64 + dbase]);
#pragma unroll
            for (int q = 0; q < 4; ++q) {
                float4 w1 = w1p[q];
                float4 w2 = w2p[q];
                acc1[q * 4 + 0] += a * w1.x;
                acc1[q * 4 + 1] += a * w1.y;
                acc1[q * 4 + 2] += a * w1.z;
                acc1[q * 4 + 3] += a * w1.w;
                acc2[q * 4 + 0] += m * w2.x;
                acc2[q * 4 + 1] += m * w2.y;
                acc2[q * 4 + 2] += m * w2.z;
                acc2[q * 4 + 3] += m * w2.w;
            }
        }

        const int n = base + lane;
        if (n < NN) {
#pragma unroll
            for (int q = 0; q < 4; ++q) {
                float r[4];
#pragma unroll
                for (int j = 0; j < 4; ++j) {
                    float x1 = acc1[q * 4 + j];
                    float x2 = acc2[q * 4 + j];
                    x1 = x1 >= 0.f ? x1 : 0.2f * x1;
                    x2 = x2 >= 0.f ? x2 : 0.2f * x2;
                    r[j] = x1 + x2;
                }
                *reinterpret_cast<float4*>(&out[(size_t)n * D + dbase + q * 4]) =
                    make_float4(r[0], r[1], r[2], r[3]);
            }
        }
    }
}

extern "C" void kernel_launch(void* const* d_in, const int* in_sizes, int n_in,
                              void* d_out, int out_size, void* d_ws, size_t ws_size,
                              hipStream_t stream) {
    const int* rows = (const int*)d_in[0];
    const int* cols = (const int*)d_in[1];
    const float* vals = (const float*)d_in[2];
    const float* feat = (const float*)d_in[3];
    const float* W1 = (const float*)d_in[4];
    const float* b1 = (const float*)d_in[5];
    const float* W2 = (const float*)d_in[6];
    const float* b2 = (const float*)d_in[7];
    float* out = (float*)d_out;

    char* ws = (char*)d_ws;
    unsigned short* agg16 = (unsigned short*)(ws + OFF_AGG16);
    int* rs = (int*)(ws + OFF_RS);
    int* cnt = (int*)(ws + OFF_CNT);
    int* bsum = (int*)(ws + OFF_BS);
    int* col_s = (int*)(ws + OFF_CS);
    float* val_s = (float*)(ws + OFF_VS);
    unsigned short* feat16 = (unsigned short*)(ws + OFF_F16);

    // feat -> bf16 (independent of CSR build)
    conv_k<<<(NN * D / 8 + 255) / 256, 256, 0, stream>>>(feat, feat16);

    // CSR build: hist -> scan -> reorder
    hipMemsetAsync(cnt, 0, NN * sizeof(int), stream);
    hist_k<<<2048, 256, 0, stream>>>(rows, cnt);
    scan1_k<<<NSB, 256, 0, stream>>>(cnt, rs, bsum);
    hipMemsetAsync(cnt, 0, NN * sizeof(int), stream);  // reuse as cursor
    scan2_k<<<1, 128, 0, stream>>>(bsum);
    scan3_k<<<(NN + 255) / 256, 256, 0, stream>>>(rs, bsum);
    reorder_k<<<2048, 256, 0, stream>>>(rows, cols, vals, rs, cnt, col_s, val_s);

    // per-row aggregation (no atomics)
    gather_k<<<(NN + 3) / 4, 256, 0, stream>>>(rs, col_s, val_s, feat16, agg16);

    // MLP
    const int ntiles = (NN + 63) / 64;
    mlp_k<<<ntiles, 256, 0, stream>>>(agg16, feat, W1, b1, W2, b2, out);
}

// Round 12
// 261.959 us; speedup vs baseline: 1.1214x; 1.1214x over previous
//
#include <hip/hip_runtime.h>

#define NN 100000
#define NE 1600000
#define D 64
#define SCAN_BLK 1024
#define NSB ((NN + SCAN_BLK - 1) / SCAN_BLK)  // 98
#define NPART 4                               // reorder row-partitions

// ---------------- ws layout (bytes), total 39,200,640 (proven cap) ---------
// agg16  : [0, 12800000)            NN*D bf16
// rs     : [12800000, +400128)      NN+1 int
// cnt    : [13200128, +400000)      NN int (hist, then cursor)
// bsum   : [13600128, +512)         NSB int
// edge_s : [13600640, +12800000)    NE int2 (col, val-bits) row-sorted
// feat16 : [26400640, +12800000)    NN*D bf16
static constexpr size_t OFF_AGG16 = 0;
static constexpr size_t OFF_RS    = 12800000;
static constexpr size_t OFF_CNT   = 13200128;
static constexpr size_t OFF_BS    = 13600128;
static constexpr size_t OFF_ES    = 13600640;
static constexpr size_t OFF_F16   = 26400640;

__device__ __forceinline__ unsigned short f32_to_bf16_rn(float x) {
    unsigned int u = __float_as_uint(x);
    u += 0x7FFFu + ((u >> 16) & 1u);  // round-to-nearest-even
    return (unsigned short)(u >> 16);
}
__device__ __forceinline__ float bf16_to_f32(unsigned int lo16) {
    return __uint_as_float(lo16 << 16);
}

// 0) feat f32 -> bf16 (8 elems/thread)
__global__ __launch_bounds__(256) void conv_k(const float* __restrict__ feat,
                                              unsigned short* __restrict__ feat16) {
    int i = blockIdx.x * blockDim.x + threadIdx.x;  // unit of 8 elems
    if (i >= NN * D / 8) return;
    const float4 f0 = *reinterpret_cast<const float4*>(&feat[i * 8]);
    const float4 f1 = *reinterpret_cast<const float4*>(&feat[i * 8 + 4]);
    uint4 o;
    o.x = f32_to_bf16_rn(f0.x) | ((unsigned int)f32_to_bf16_rn(f0.y) << 16);
    o.y = f32_to_bf16_rn(f0.z) | ((unsigned int)f32_to_bf16_rn(f0.w) << 16);
    o.z = f32_to_bf16_rn(f1.x) | ((unsigned int)f32_to_bf16_rn(f1.y) << 16);
    o.w = f32_to_bf16_rn(f1.z) | ((unsigned int)f32_to_bf16_rn(f1.w) << 16);
    *reinterpret_cast<uint4*>(&feat16[i * 8]) = o;
}

// 1) histogram of rows
__global__ __launch_bounds__(256) void hist_k(const int* __restrict__ rows,
                                              int* __restrict__ cnt) {
    int stride = gridDim.x * blockDim.x;
    for (int e = blockIdx.x * blockDim.x + threadIdx.x; e < NE; e += stride)
        atomicAdd(&cnt[rows[e]], 1);
}

// 2a) per-1024-block exclusive scan; block sums out
__global__ __launch_bounds__(256) void scan1_k(const int* __restrict__ cnt,
                                               int* __restrict__ rs,
                                               int* __restrict__ bsum) {
    __shared__ int tsum[256];
    const int b = blockIdx.x;
    const int base = b * SCAN_BLK + threadIdx.x * 4;
    int v[4];
    int s = 0;
#pragma unroll
    for (int i = 0; i < 4; ++i) {
        int idx = base + i;
        v[i] = (idx < NN) ? cnt[idx] : 0;
        s += v[i];
    }
    tsum[threadIdx.x] = s;
    __syncthreads();
    int x = s;
    for (int off = 1; off < 256; off <<= 1) {
        int y = (threadIdx.x >= off) ? tsum[threadIdx.x - off] : 0;
        __syncthreads();
        x += y;
        tsum[threadIdx.x] = x;
        __syncthreads();
    }
    int run = x - s;
#pragma unroll
    for (int i = 0; i < 4; ++i) {
        int idx = base + i;
        if (idx < NN) rs[idx] = run;
        run += v[i];
    }
    if (threadIdx.x == 255) bsum[b] = x;
}

// 2b) exclusive scan of NSB block sums
__global__ void scan2_k(int* __restrict__ bsum) {
    __shared__ int s[128];
    int i = threadIdx.x;
    int v = (i < NSB) ? bsum[i] : 0;
    s[i] = v;
    __syncthreads();
    int x = v;
    for (int off = 1; off < 128; off <<= 1) {
        int y = (i >= off) ? s[i - off] : 0;
        __syncthreads();
        x += y;
        s[i] = x;
        __syncthreads();
    }
    if (i < NSB) bsum[i] = x - v;  // exclusive
}

// 2c) add block offsets; cap entry
__global__ __launch_bounds__(256) void scan3_k(int* __restrict__ rs,
                                               const int* __restrict__ bsum) {
    int i = blockIdx.x * blockDim.x + threadIdx.x;
    if (i < NN) rs[i] += bsum[i >> 10];
    if (i == 0) rs[NN] = NE;
}

// 3) reorder, row-partitioned: blockIdx.y = partition p owns rows
//    [p*25000, (p+1)*25000); each partition re-scans all edges and writes only
//    its own contiguous ~3.2 MB slice of edge_s -> lines fill while L2-resident
//    (fix for 154 MB of line-writeback amplification at 8B/line useful).
__global__ __launch_bounds__(256) void reorder_k(const int* __restrict__ rows,
                                                 const int* __restrict__ cols,
                                                 const float* __restrict__ vals,
                                                 const int* __restrict__ rs,
                                                 int* __restrict__ cur,
                                                 int2* __restrict__ edge_s) {
    const int lo = blockIdx.y * (NN / NPART);
    const int hi = lo + (NN / NPART);
    int stride = gridDim.x * blockDim.x;
    for (int e = blockIdx.x * blockDim.x + threadIdx.x; e < NE; e += stride) {
        int r = rows[e];
        if (r >= lo && r < hi) {
            int p = rs[r] + atomicAdd(&cur[r], 1);
            edge_s[p] = make_int2(cols[e], __float_as_int(vals[e]));
        }
    }
}

// 4) per-row gather-reduce, 8 edges in flight per wave, bf16 feat rows (128B
//    = 2 cache lines). lane = group g (lane>>3) x slot t (lane&7); group g
//    handles edge 8*jj+g; lane loads uint4 (8 bf16) of the neighbor row.
//    Cross-group shfl_xor(8,16,32) reduce; lanes 0-7 write the bf16 agg row.
__global__ __launch_bounds__(256) void gather_k(const int* __restrict__ rs,
                                                const int2* __restrict__ edge_s,
                                                const unsigned short* __restrict__ feat16,
                                                unsigned short* __restrict__ agg16) {
    const int lane = threadIdx.x & 63;
    const int g = lane >> 3;
    const int t = lane & 7;
    const int r = blockIdx.x * 4 + (threadIdx.x >> 6);
    if (r >= NN) return;
    const int s = rs[r], e = rs[r + 1];

    float acc[8];
#pragma unroll
    for (int k = 0; k < 8; ++k) acc[k] = 0.f;

    for (int base = s; base < e; base += 64) {
        int n = e - base;
        if (n > 64) n = 64;
        int c = 0;
        float v = 0.f;
        if (lane < n) {
            int2 ev = edge_s[base + lane];
            c = ev.x;
            v = __int_as_float(ev.y);
        }
        const int niter = (n + 7) >> 3;
        for (int jj = 0; jj < niter; ++jj) {
            int src = (jj << 3) + g;     // my group's edge slot
            int cj = __shfl(c, src);     // 0 if src >= n (row 0, harmless)
            float vj = __shfl(v, src);   // 0 if src >= n (no contribution)
            const uint4 f =
                *reinterpret_cast<const uint4*>(&feat16[(size_t)cj * D + (t << 3)]);
            acc[0] += vj * bf16_to_f32(f.x & 0xffffu);
            acc[1] += vj * bf16_to_f32(f.x >> 16);
            acc[2] += vj * bf16_to_f32(f.y & 0xffffu);
            acc[3] += vj * bf16_to_f32(f.y >> 16);
            acc[4] += vj * bf16_to_f32(f.z & 0xffffu);
            acc[5] += vj * bf16_to_f32(f.z >> 16);
            acc[6] += vj * bf16_to_f32(f.w & 0xffffu);
            acc[7] += vj * bf16_to_f32(f.w >> 16);
        }
    }
#pragma unroll
    for (int off = 8; off <= 32; off <<= 1) {
#pragma unroll
        for (int k = 0; k < 8; ++k) acc[k] += __shfl_xor(acc[k], off);
    }
    if (lane < 8) {
        uint4 o;
        o.x = f32_to_bf16_rn(acc[0]) | ((unsigned int)f32_to_bf16_rn(acc[1]) << 16);
        o.y = f32_to_bf16_rn(acc[2]) | ((unsigned int)f32_to_bf16_rn(acc[3]) << 16);
        o.z = f32_to_bf16_rn(acc[4]) | ((unsigned int)f32_to_bf16_rn(acc[5]) << 16);
        o.w = f32_to_bf16_rn(acc[6]) | ((unsigned int)f32_to_bf16_rn(acc[7]) << 16);
        *reinterpret_cast<uint4*>(&agg16[(size_t)r * D + (t << 3)]) = o;
    }
}

// 5) out = leaky(agg@W1+b1) + leaky((agg*feat)@W2+b2); agg in bf16
__global__ __launch_bounds__(256) void mlp_k(const unsigned short* __restrict__ agg16,
                                             const float* __restrict__ feat,
                                             const float* __restrict__ W1,
                                             const float* __restrict__ b1,
                                             const float* __restrict__ W2,
                                             const float* __restrict__ b2,
                                             float* __restrict__ out) {
    __shared__ float W1s[64 * 64];
    __shared__ float W2s[64 * 64];
    __shared__ float b1s[64], b2s[64];
    __shared__ float As[64][65];
    __shared__ float Ms[64][65];

    for (int i = threadIdx.x; i < 4096; i += 256) {
        W1s[i] = W1[i];
        W2s[i] = W2[i];
    }
    if (threadIdx.x < 64) {
        b1s[threadIdx.x] = b1[threadIdx.x];
        b2s[threadIdx.x] = b2[threadIdx.x];
    }

    const int wv = threadIdx.x >> 6;
    const int lane = threadIdx.x & 63;
    const int ntiles = (NN + 63) / 64;

    for (int t = blockIdx.x; t < ntiles; t += gridDim.x) {
        const int base = t * 64;
        __syncthreads();
        // stage: 64 rows x 8 segments of 8 elems; 512 units over 256 threads
        for (int i = threadIdx.x; i < 512; i += 256) {
            int row = i >> 3;
            int sg = i & 7;
            int n = base + row;
            uint4 a16 = make_uint4(0, 0, 0, 0);
            float4 f0 = make_float4(0.f, 0.f, 0.f, 0.f);
            float4 f1 = make_float4(0.f, 0.f, 0.f, 0.f);
            if (n < NN) {
                a16 = *reinterpret_cast<const uint4*>(&agg16[(size_t)n * D + sg * 8]);
                f0 = *reinterpret_cast<const float4*>(&feat[(size_t)n * D + sg * 8]);
                f1 = *reinterpret_cast<const float4*>(&feat[(size_t)n * D + sg * 8 + 4]);
            }
            float a[8];
            a[0] = bf16_to_f32(a16.x & 0xffffu);
            a[1] = bf16_to_f32(a16.x >> 16);
            a[2] = bf16_to_f32(a16.y & 0xffffu);
            a[3] = bf16_to_f32(a16.y >> 16);
            a[4] = bf16_to_f32(a16.z & 0xffffu);
            a[5] = bf16_to_f32(a16.z >> 16);
            a[6] = bf16_to_f32(a16.w & 0xffffu);
            a[7] = bf16_to_f32(a16.w >> 16);
            float f[8] = {f0.x, f0.y, f0.z, f0.w, f1.x, f1.y, f1.z, f1.w};
#pragma unroll
            for (int k = 0; k < 8; ++k) {
                As[row][sg * 8 + k] = a[k];
                Ms[row][sg * 8 + k] = a[k] * f[k];
            }
        }
        __syncthreads();

        const int dbase = wv * 16;
        float acc1[16], acc2[16];
#pragma unroll
        for (int j = 0; j < 16; ++j) {
            acc1[j] = b1s[dbase + j];
            acc2[j] = b2s[dbase + j];
        }
#pragma unroll 8
        for (int k = 0; k < 64; ++k) {
            float a = As[lane][k];
            float m = Ms[lane][k];
            const float4* w1p = reinterpret_cast<const float4*>(&W1s[k * 64 + dbase]);
            const float4* w2p = reinterpret_cast<const float4*>(&W2s[k * 64 + dbase]);
#pragma unroll
            for (int q = 0; q < 4; ++q) {
                float4 w1 = w1p[q];
                float4 w2 = w2p[q];
                acc1[q * 4 + 0] += a * w1.x;
                acc1[q * 4 + 1] += a * w1.y;
                acc1[q * 4 + 2] += a * w1.z;
                acc1[q * 4 + 3] += a * w1.w;
                acc2[q * 4 + 0] += m * w2.x;
                acc2[q * 4 + 1] += m * w2.y;
                acc2[q * 4 + 2] += m * w2.z;
                acc2[q * 4 + 3] += m * w2.w;
            }
        }

        const int n = base + lane;
        if (n < NN) {
#pragma unroll
            for (int q = 0; q < 4; ++q) {
                float r[4];
#pragma unroll
                for (int j = 0; j < 4; ++j) {
                    float x1 = acc1[q * 4 + j];
                    float x2 = acc2[q * 4 + j];
                    x1 = x1 >= 0.f ? x1 : 0.2f * x1;
                    x2 = x2 >= 0.f ? x2 : 0.2f * x2;
                    r[j] = x1 + x2;
                }
                *reinterpret_cast<float4*>(&out[(size_t)n * D + dbase + q * 4]) =
                    make_float4(r[0], r[1], r[2], r[3]);
            }
        }
    }
}

extern "C" void kernel_launch(void* const* d_in, const int* in_sizes, int n_in,
                              void* d_out, int out_size, void* d_ws, size_t ws_size,
                              hipStream_t stream) {
    const int* rows = (const int*)d_in[0];
    const int* cols = (const int*)d_in[1];
    const float* vals = (const float*)d_in[2];
    const float* feat = (const float*)d_in[3];
    const float* W1 = (const float*)d_in[4];
    const float* b1 = (const float*)d_in[5];
    const float* W2 = (const float*)d_in[6];
    const float* b2 = (const float*)d_in[7];
    float* out = (float*)d_out;

    char* ws = (char*)d_ws;
    unsigned short* agg16 = (unsigned short*)(ws + OFF_AGG16);
    int* rs = (int*)(ws + OFF_RS);
    int* cnt = (int*)(ws + OFF_CNT);
    int* bsum = (int*)(ws + OFF_BS);
    int2* edge_s = (int2*)(ws + OFF_ES);
    unsigned short* feat16 = (unsigned short*)(ws + OFF_F16);

    // feat -> bf16 (independent of CSR build)
    conv_k<<<(NN * D / 8 + 255) / 256, 256, 0, stream>>>(feat, feat16);

    // CSR build: hist -> scan -> partitioned reorder
    hipMemsetAsync(cnt, 0, NN * sizeof(int), stream);
    hist_k<<<2048, 256, 0, stream>>>(rows, cnt);
    scan1_k<<<NSB, 256, 0, stream>>>(cnt, rs, bsum);
    hipMemsetAsync(cnt, 0, NN * sizeof(int), stream);  // reuse as cursor
    scan2_k<<<1, 128, 0, stream>>>(bsum);
    scan3_k<<<(NN + 255) / 256, 256, 0, stream>>>(rs, bsum);
    {
        dim3 grid(1024, NPART);
        reorder_k<<<grid, 256, 0, stream>>>(rows, cols, vals, rs, cnt, edge_s);
    }

    // per-row aggregation (no atomics)
    gather_k<<<(NN + 3) / 4, 256, 0, stream>>>(rs, edge_s, feat16, agg16);

    // MLP
    const int ntiles = (NN + 63) / 64;
    mlp_k<<<ntiles, 256, 0, stream>>>(agg16, feat, W1, b1, W2, b2, out);
}